// Round 7
// baseline (194.406 us; speedup 1.0000x reference)
//
#include <hip/hip_runtime.h>
#include <hip/hip_fp16.h>

// LBP semantic dependency, channel-difference form, base-2 domain.
//   d'(x,p) = sp(x+p) - sp(x);  db[a,u] = edge + sum_{v!=a,u} sum_t d'-terms
// All db quantities in units of ln2. tp = e^p quantized fp16 (same point as
// R14 -> numerics preserved).
// R15 = R14 with per-tensor slab re-staging for 2 blocks/CU:
//   R14 counters: 0.65 TB/s, VALUBusy 33%, LDS 163KB -> 1 block/CU, grid 320
//   -> TWO dispatch rounds (round 2 on 64 CUs = 75% idle) and 3.75 waves/SIMD
//   can't hide trans-chain latency. The t-sum is separable in every phase:
//   stage ONE 160x162 fp16 slab (51.8KB), loop t, re-stage for d2/d3 passes
//   (reads are L3-resident; +exp2 recompute ~1.6us/slice). LDS 163->68KB ->
//   2 blocks/CU, one packed round, 20 waves/CU.
//   Staging order A:0,1,2(keep 0? no: keep t0 written), B:0*,1,2, C:2*,0,1
//   (* = already in slab) -> 5 stagings not 9. Exclusion/di terms (3x160
//   values) read direct from global with quantize-roundtrip.

#define S    160
#define S2   25600            // 160*160
#define S3   4096000          // 160^3 (per-n slab, elements)
#define STR  162              // LDS slab row stride in halves
#define C2E  1.4426950408889634f

__device__ __forceinline__ float fexp2(float x) { return __builtin_amdgcn_exp2f(x); }
__device__ __forceinline__ float flog2(float x) { return __builtin_amdgcn_logf(x); }
__device__ __forceinline__ float frcp(float x)  { return __builtin_amdgcn_rcpf(x); }
__device__ __forceinline__ float cdb(float x) {
    return fminf(fmaxf(x, -100.f), 100.f);   // keeps exp2 finite; terms saturated anyway
}
__device__ __forceinline__ float sp2t(float tp) { return flog2(1.f + tp); }
__device__ __forceinline__ float Ff(float x, float tp) {
    float tx = fexp2(x);
    return flog2(1.f + tx * tp) - flog2(1.f + tx);
}
__device__ __forceinline__ const float* selT(int t, const float* a,
                                             const float* b, const float* c) {
    return (t == 0) ? a : (t == 1) ? b : c;
}

// One block per slice (n,a). 640 threads (10 waves), ~68KB LDS -> 2 blocks/CU.
__global__ __launch_bounds__(640)
void k_fused(const float* __restrict__ s_sib, const float* __restrict__ s_cop,
             const float* __restrict__ s_grd, const float* __restrict__ s_edge,
             float* __restrict__ outp)
{
    int slice = blockIdx.x;           // 0..319
    int a = slice % S, n = slice / S;
    int tid = threadIdx.x;
    int u4 = tid % 40, vsg = tid / 40;    // staging map (vsg 0..15)
    int us = tid % S,  vs = tid / S;      // sweep map   (vs 0..3)

    __shared__ __half slab[S * STR];      // one tensor's tp[v][u]   (51,840 B)
    __shared__ float  scr[2560];          // ph1 partials / sweep partials (10,240 B)
    __shared__ float  db1s[S], db2s[S], E1[S], E2[S];          // (2,560 B)
    __shared__ __half rowA[3][S], colA[3][S], diagA[3][S];     // (2,880 B)

    // ---- pass A: ph1 streaming (global->reg, no LDS dependency). Writes the
    // slab only for t==0 (pass B's first tensor). acc = per-thread fp32
    // partial of Sum_{t, v in subset} log2(1+tp) for its 4 u's.
    float4 acc = make_float4(0.f, 0.f, 0.f, 0.f);
    #pragma unroll
    for (int t = 0; t < 3; ++t) {
        const float* g = selT(t, s_sib, s_cop, s_grd)
                       + (long)n * S3 + (long)a * S + u4 * 4;
        float4 pv[10];
        #pragma unroll
        for (int j = 0; j < 10; ++j)
            pv[j] = *(const float4*)(g + (long)(j * 16 + vsg) * S2);
        #pragma unroll
        for (int j = 0; j < 10; ++j) {
            float t0 = fexp2(pv[j].x * C2E), t1 = fexp2(pv[j].y * C2E);
            float t2 = fexp2(pv[j].z * C2E), t3 = fexp2(pv[j].w * C2E);
            acc.x += flog2(1.f + t0); acc.y += flog2(1.f + t1);
            acc.z += flog2(1.f + t2); acc.w += flog2(1.f + t3);
            if (t == 0) {
                __half* b = &slab[(j * 16 + vsg) * STR + u4 * 4];
                *(__half2*)(b)     = __floats2half2_rn(t0, t1);
                *(__half2*)(b + 2) = __floats2half2_rn(t2, t3);
            }
        }
    }
    // exclusion terms + di-term captures (quantize-roundtrip = slab numerics)
    float excl = 0.f, edg = 0.f;
    if (tid < S) {
        int u = tid;
        edg = s_edge[n * S2 + u * S + a] * C2E;
        #pragma unroll
        for (int t = 0; t < 3; ++t) {
            const float* base = selT(t, s_sib, s_cop, s_grd)
                              + (long)n * S3 + (long)a * S;   // + v*S2 + col
            __half ha  = __float2half_rn(fexp2(base[(long)a * S2 + u] * C2E)); // tp(a,u)
            __half hba = __float2half_rn(fexp2(base[(long)u * S2 + a] * C2E)); // tp(u,a)
            __half hu  = __float2half_rn(fexp2(base[(long)u * S2 + u] * C2E)); // tp(u,u)
            rowA[t][u] = ha; colA[t][u] = hba; diagA[t][u] = hu;
            excl -= (sp2t(__half2float(ha)) - 1.f);
            if (u != a) excl -= (sp2t(__half2float(hu)) - 1.f);
        }
    }
    ((float4*)scr)[vsg * 40 + u4] = acc;
    __syncthreads();
    // ---- db1 + E1
    if (tid < S) {
        int u = tid, cu4 = u >> 2, cc = u & 3;
        float s = 0.f;
        #pragma unroll
        for (int g2 = 0; g2 < 16; ++g2) s += scr[(g2 * 40 + cu4) * 4 + cc];
        float r = edg + s - 480.f + excl;
        db1s[u] = r;
        E1[u] = fexp2(cdb(r) + 1.f);
    }

    // ---- pass B: d2 sweep, t = 0(pre-staged),1,2
    float d2acc = 0.f;
    #pragma unroll
    for (int t = 0; t < 3; ++t) {
        __syncthreads();              // prev sweep done / E1 visible
        if (t != 0) {
            const float* g = selT(t, s_sib, s_cop, s_grd)
                           + (long)n * S3 + (long)a * S + u4 * 4;
            float4 pv[10];
            #pragma unroll
            for (int j = 0; j < 10; ++j)
                pv[j] = *(const float4*)(g + (long)(j * 16 + vsg) * S2);
            #pragma unroll
            for (int j = 0; j < 10; ++j) {
                float t0 = fexp2(pv[j].x * C2E), t1 = fexp2(pv[j].y * C2E);
                float t2 = fexp2(pv[j].z * C2E), t3 = fexp2(pv[j].w * C2E);
                __half* b = &slab[(j * 16 + vsg) * STR + u4 * 4];
                *(__half2*)(b)     = __floats2half2_rn(t0, t1);
                *(__half2*)(b + 2) = __floats2half2_rn(t2, t3);
            }
            __syncthreads();
        }
        #pragma unroll 4
        for (int k = 0; k < 40; ++k) {
            int v = k * 4 + vs;
            float tA = __half2float(slab[v * STR + us]);   // tp(v,u)
            float tB = __half2float(slab[us * STR + v]);   // tp(u,v)
            float e  = E1[v] * frcp(1.f + tB);             // 2^(db1[v]+1-sp2t(tB))
            d2acc += flog2(1.f + e * tA) - flog2(1.f + e);
        }
    }
    scr[vs * S + us] = d2acc;
    __syncthreads();
    // ---- db2 (inline di2) + E2
    if (tid < S) {
        int u = tid;
        float sw = scr[u] + scr[S + u] + scr[2 * S + u] + scr[3 * S + u];
        float db1a1 = cdb(db1s[a]) + 1.f;
        float db1u1 = cdb(db1s[u]) + 1.f;
        float sum = 0.f;
        #pragma unroll
        for (int t = 0; t < 3; ++t) {
            float tpa  = __half2float(rowA[t][u]);
            float tpba = __half2float(colA[t][u]);
            sum += Ff(db1a1 - sp2t(tpba), tpa);            // C2(v=a)
            if (u != a) {
                float tpu = __half2float(diagA[t][u]);
                sum += Ff(db1u1 - sp2t(tpu), tpu);         // C2(v=u)
            }
        }
        float d2v = edg - sum + sw;
        db2s[u] = d2v;
        E2[u] = fexp2(cdb(d2v));
    }

    // ---- pass C: d3 sweep, t order 2(still staged),0,1
    float d3acc = 0.f;
    float E1u_c = 0.f;
    #pragma unroll
    for (int tt = 0; tt < 3; ++tt) {
        int t = (tt == 0) ? 2 : tt - 1;
        __syncthreads();              // prev sweep done / E2 visible
        if (tt != 0) {
            const float* g = selT(t, s_sib, s_cop, s_grd)
                           + (long)n * S3 + (long)a * S + u4 * 4;
            float4 pv[10];
            #pragma unroll
            for (int j = 0; j < 10; ++j)
                pv[j] = *(const float4*)(g + (long)(j * 16 + vsg) * S2);
            #pragma unroll
            for (int j = 0; j < 10; ++j) {
                float t0 = fexp2(pv[j].x * C2E), t1 = fexp2(pv[j].y * C2E);
                float t2 = fexp2(pv[j].z * C2E), t3 = fexp2(pv[j].w * C2E);
                __half* b = &slab[(j * 16 + vsg) * STR + u4 * 4];
                *(__half2*)(b)     = __floats2half2_rn(t0, t1);
                *(__half2*)(b + 2) = __floats2half2_rn(t2, t3);
            }
            __syncthreads();
        }
        E1u_c = E1[us];               // 2^(db1[u]+1)
        #pragma unroll 4
        for (int k = 0; k < 40; ++k) {
            int v = k * 4 + vs;
            float tA = __half2float(slab[v * STR + us]);   // tp(v,u)
            float tB = __half2float(slab[us * STR + v]);   // tp(u,v)
            float rA = frcp(1.f + tA);
            float e2 = E1u_c * rA;                         // 2^(db1[u]+1-sp2t(tA))
            float w  = frcp(1.f + e2 * tB);
            float e3 = E2[v] * ((1.f + e2) * w);           // 2^(db2[v]-d2[v,u])
            d3acc += flog2(1.f + e3 * tA) - flog2(1.f + e3);
        }
    }
    scr[vs * S + us] = d3acc;
    __syncthreads();
    // ---- di3 + output
    if (tid < S) {
        int u = tid;
        float sw = scr[u] + scr[S + u] + scr[2 * S + u] + scr[3 * S + u];
        float db1u1 = cdb(db1s[u]) + 1.f;
        float db2a = cdb(db2s[a]);
        float db2u = cdb(db2s[u]);
        float sum = 0.f;
        #pragma unroll
        for (int t = 0; t < 3; ++t) {
            float tpa  = __half2float(rowA[t][u]);
            float tpba = __half2float(colA[t][u]);
            float d2vu = Ff(db1u1 - sp2t(tpa), tpba);
            sum += Ff(db2a - d2vu, tpa);                   // C3(v=a)
            if (u != a) {
                float tpu = __half2float(diagA[t][u]);
                float d2  = Ff(db1u1 - sp2t(tpu), tpu);
                sum += Ff(db2u - d2, tpu);                 // C3(v=u)
            }
        }
        float s = edg - sum + sw;
        float sc  = fminf(fmaxf(s, -60.f), 60.f);  // avoid exp2 overflow -> inf*0=NaN
        float tsg = fexp2(-sc);
        float r   = __fdividef(1.f, 1.f + tsg);
        long ob = ((long)(n * S + u) * S + a) * 2;
        *(float2*)(outp + ob) = make_float2(tsg * r, r);
    }
}

extern "C" void kernel_launch(void* const* d_in, const int* in_sizes, int n_in,
                              void* d_out, int out_size, void* d_ws, size_t ws_size,
                              hipStream_t stream) {
    const float* s_edge = (const float*)d_in[0];
    const float* s_sib  = (const float*)d_in[1];
    const float* s_cop  = (const float*)d_in[2];
    const float* s_grd  = (const float*)d_in[3];
    float* outp = (float*)d_out;
    (void)d_ws; (void)ws_size;          // workspace unused (no poison fills)

    k_fused<<<320, 640, 0, stream>>>(s_sib, s_cop, s_grd, s_edge, outp);
}

// Round 8
// 164.343 us; speedup vs baseline: 1.1829x; 1.1829x over previous
//
#include <hip/hip_runtime.h>
#include <hip/hip_fp16.h>

// LBP semantic dependency, channel-difference form, base-2 domain.
//   d'(x,p) = sp(x+p) - sp(x);  db[a,u] = edge + sum_{v!=a,u} sum_t d'-terms
// All db quantities in units of ln2. tp = e^p quantized fp16.
// R16 = R14 (3 slabs resident, stage once — R15's mid-kernel re-staging put
// global latency on the critical path: 101us, FETCH 2x) + block-time fixes:
//   R14 block = 36us vs ~14us pure-work floor, VALUBusy 33%: sweep loops had
//   2 dependent LDS loads -> use per iteration, no unroll -> lgkmcnt stall
//   every ~15cy of math at 3.75 waves/SIMD. Fixes:
//   (1) sweeps in batches of 4 (8 ds_reads batched, then math)
//   (2) staging uses all 960 threads (was 640)
//   (3) ph1 reduce: 3-stage RMW, 3 barriers (was 8); 7 barriers total
//   LDS 163,200B (= R14), 1 block/CU, grid 320 -> 2-round makespan stands.

#define S    160
#define S2   25600            // 160*160
#define S3   4096000          // 160^3 (per-n slab, elements)
#define STR  162              // LDS slab row stride in halves (bank-spread pad)
#define C2E  1.4426950408889634f

__device__ __forceinline__ float fexp2(float x) { return __builtin_amdgcn_exp2f(x); }
__device__ __forceinline__ float flog2(float x) { return __builtin_amdgcn_logf(x); }
__device__ __forceinline__ float frcp(float x)  { return __builtin_amdgcn_rcpf(x); }
__device__ __forceinline__ float cdb(float x) {
    return fminf(fmaxf(x, -100.f), 100.f);   // keeps exp2 finite; terms saturated anyway
}
__device__ __forceinline__ float sp2t(float tp) { return flog2(1.f + tp); }
__device__ __forceinline__ float Ff(float x, float tp) {
    float tx = fexp2(x);
    return flog2(1.f + tx * tp) - flog2(1.f + tx);
}
__device__ __forceinline__ const float* selT(int t, const float* a,
                                             const float* b, const float* c) {
    return (t == 0) ? a : (t == 1) ? b : c;
}

// One block per slice (n,a). 960 threads (15 waves), 163,200B LDS -> 1 blk/CU.
__global__ __launch_bounds__(960)
void k_fused(const float* __restrict__ s_sib, const float* __restrict__ s_cop,
             const float* __restrict__ s_grd, const float* __restrict__ s_edge,
             float* __restrict__ outp)
{
    int slice = blockIdx.x;           // 0..319
    int a = slice % S, n = slice / S;
    int tid = threadIdx.x;
    int u4 = tid % 40, r = tid / 40;      // staging map (r 0..23, v = r+24i)
    int us = tid % S,  vs = tid / S;      // sweep map   (vs 0..5, v = 6k+vs)

    __shared__ __half tp3[3 * S * STR];   // tp3[t][v][u]           (155,520 B)
    __shared__ float  scr[1280];          // ph1 float4 partials / sweep partials (5,120 B)
    __shared__ float  db1s[S], db2s[S], E1[S], E2[S];               // (2,560 B)

    // ---- staging: all 960 threads; per tensor, thread loads v = r+24i
    // (i<6 all, i=6 only r<16), all misses in flight, converts, writes slab,
    // accumulates fp32 ph1 partial for its fixed u4-column.
    float4 acc = make_float4(0.f, 0.f, 0.f, 0.f);
    float edg = 0.f;
    if (tid < S) edg = s_edge[n * S2 + tid * S + a] * C2E;
    #pragma unroll
    for (int t = 0; t < 3; ++t) {
        const float* g = selT(t, s_sib, s_cop, s_grd)
                       + (long)n * S3 + (long)a * S + u4 * 4;
        float4 pv[7];
        #pragma unroll
        for (int i = 0; i < 6; ++i)
            pv[i] = *(const float4*)(g + (long)(r + 24 * i) * S2);
        if (r < 16) pv[6] = *(const float4*)(g + (long)(r + 144) * S2);
        #pragma unroll
        for (int i = 0; i < 7; ++i) {
            if (i == 6 && r >= 16) break;
            int v = r + 24 * i;
            float t0 = fexp2(pv[i].x * C2E), t1 = fexp2(pv[i].y * C2E);
            float t2 = fexp2(pv[i].z * C2E), t3 = fexp2(pv[i].w * C2E);
            acc.x += flog2(1.f + t0); acc.y += flog2(1.f + t1);
            acc.z += flog2(1.f + t2); acc.w += flog2(1.f + t3);
            __half* b = &tp3[t * (S * STR) + v * STR + u4 * 4];
            *(__half2*)(b)     = __floats2half2_rn(t0, t1);
            *(__half2*)(b + 2) = __floats2half2_rn(t2, t3);
        }
    }
    // ---- ph1 reduce: 24 r-groups -> 8 (3-stage RMW) -> db1
    float4* scr4 = (float4*)scr;
    if (r < 8) scr4[r * 40 + u4] = acc;
    __syncthreads();
    if (r >= 8 && r < 16) {
        float4 o = scr4[(r - 8) * 40 + u4];
        o.x += acc.x; o.y += acc.y; o.z += acc.z; o.w += acc.w;
        scr4[(r - 8) * 40 + u4] = o;
    }
    __syncthreads();
    if (r >= 16) {
        float4 o = scr4[(r - 16) * 40 + u4];
        o.x += acc.x; o.y += acc.y; o.z += acc.z; o.w += acc.w;
        scr4[(r - 16) * 40 + u4] = o;
    }
    __syncthreads();
    // ---- db1 + E1 (exclusion terms read from quantized slabs = R14 numerics)
    if (tid < S) {
        int u = tid, cu4 = u >> 2, cc = u & 3;
        float s = 0.f;
        #pragma unroll
        for (int g2 = 0; g2 < 8; ++g2) s += scr[(g2 * 40 + cu4) * 4 + cc];
        float rr = edg + s - 480.f;
        #pragma unroll
        for (int t = 0; t < 3; ++t) {
            const __half* sl = &tp3[t * (S * STR)];
            float tpa = __half2float(sl[a * STR + u]);    // tp(v=a, u)
            rr -= (sp2t(tpa) - 1.f);
            if (u != a) {
                float tpu = __half2float(sl[u * STR + u]);
                rr -= (sp2t(tpu) - 1.f);
            }
        }
        db1s[u] = rr;
        E1[u] = fexp2(cdb(rr) + 1.f);
    }
    __syncthreads();

    // ---- d2 sweep: batches of 4 (8 ds_reads grouped, then math)
    float d2acc = 0.f;
    #pragma unroll
    for (int t = 0; t < 3; ++t) {
        const __half* sl = &tp3[t * (S * STR)];
        for (int kb = 0; kb < 6; ++kb) {
            float tA[4], tB[4], Ev[4];
            #pragma unroll
            for (int j = 0; j < 4; ++j) {
                int v = (kb * 4 + j) * 6 + vs;
                tA[j] = __half2float(sl[v * STR + us]);
                tB[j] = __half2float(sl[us * STR + v]);
                Ev[j] = E1[v];
            }
            #pragma unroll
            for (int j = 0; j < 4; ++j) {
                float e = Ev[j] * frcp(1.f + tB[j]);
                d2acc += flog2(1.f + e * tA[j]) - flog2(1.f + e);
            }
        }
        #pragma unroll
        for (int k = 24; k < 27; ++k) {
            int v = k * 6 + vs;
            if (v < S) {
                float tA = __half2float(sl[v * STR + us]);
                float tB = __half2float(sl[us * STR + v]);
                float e  = E1[v] * frcp(1.f + tB);
                d2acc += flog2(1.f + e * tA) - flog2(1.f + e);
            }
        }
    }
    scr[vs * S + us] = d2acc;
    __syncthreads();
    // ---- db2 (inline di2) + E2
    if (tid < S) {
        int u = tid;
        float sw = scr[u] + scr[S + u] + scr[2 * S + u] + scr[3 * S + u]
                 + scr[4 * S + u] + scr[5 * S + u];
        float db1a1 = cdb(db1s[a]) + 1.f;
        float db1u1 = cdb(db1s[u]) + 1.f;
        float sum = 0.f;
        #pragma unroll
        for (int t = 0; t < 3; ++t) {
            const __half* sl = &tp3[t * (S * STR)];
            float tpa  = __half2float(sl[a * STR + u]);   // tp(v=a, u)
            float tpba = __half2float(sl[u * STR + a]);   // tp(u, v=a)
            sum += Ff(db1a1 - sp2t(tpba), tpa);           // C2(v=a)
            if (u != a) {
                float tpu = __half2float(sl[u * STR + u]);
                sum += Ff(db1u1 - sp2t(tpu), tpu);        // C2(v=u)
            }
        }
        float d2v = edg - sum + sw;
        db2s[u] = d2v;
        E2[u] = fexp2(cdb(d2v));
    }
    __syncthreads();

    // ---- d3 sweep: batches of 4
    float d3acc = 0.f;
    float E1u = E1[us];                  // 2^(db1[u]+1)
    #pragma unroll
    for (int t = 0; t < 3; ++t) {
        const __half* sl = &tp3[t * (S * STR)];
        for (int kb = 0; kb < 6; ++kb) {
            float tA[4], tB[4], Ev[4];
            #pragma unroll
            for (int j = 0; j < 4; ++j) {
                int v = (kb * 4 + j) * 6 + vs;
                tA[j] = __half2float(sl[v * STR + us]);
                tB[j] = __half2float(sl[us * STR + v]);
                Ev[j] = E2[v];
            }
            #pragma unroll
            for (int j = 0; j < 4; ++j) {
                float rA = frcp(1.f + tA[j]);
                float e2 = E1u * rA;                      // 2^(db1[u]+1-sp2t(tA))
                float w  = frcp(1.f + e2 * tB[j]);
                float e3 = Ev[j] * ((1.f + e2) * w);      // 2^(db2[v]-d2[v,u])
                d3acc += flog2(1.f + e3 * tA[j]) - flog2(1.f + e3);
            }
        }
        #pragma unroll
        for (int k = 24; k < 27; ++k) {
            int v = k * 6 + vs;
            if (v < S) {
                float tA = __half2float(sl[v * STR + us]);
                float tB = __half2float(sl[us * STR + v]);
                float rA = frcp(1.f + tA);
                float e2 = E1u * rA;
                float w  = frcp(1.f + e2 * tB);
                float e3 = E2[v] * ((1.f + e2) * w);
                d3acc += flog2(1.f + e3 * tA) - flog2(1.f + e3);
            }
        }
    }
    scr[vs * S + us] = d3acc;
    __syncthreads();
    // ---- di3 + output
    if (tid < S) {
        int u = tid;
        float sw = scr[u] + scr[S + u] + scr[2 * S + u] + scr[3 * S + u]
                 + scr[4 * S + u] + scr[5 * S + u];
        float db1u1 = cdb(db1s[u]) + 1.f;
        float db2a = cdb(db2s[a]);
        float db2u = cdb(db2s[u]);
        float sum = 0.f;
        #pragma unroll
        for (int t = 0; t < 3; ++t) {
            const __half* sl = &tp3[t * (S * STR)];
            float tpa  = __half2float(sl[a * STR + u]);   // tp(v=a, u)
            float tpba = __half2float(sl[u * STR + a]);   // tp(u, v=a)
            float d2vu = Ff(db1u1 - sp2t(tpa), tpba);
            sum += Ff(db2a - d2vu, tpa);                  // C3(v=a)
            if (u != a) {
                float tpu = __half2float(sl[u * STR + u]);
                float d2  = Ff(db1u1 - sp2t(tpu), tpu);
                sum += Ff(db2u - d2, tpu);                // C3(v=u)
            }
        }
        float s = edg - sum + sw;
        float sc  = fminf(fmaxf(s, -60.f), 60.f);  // avoid exp2 overflow -> inf*0=NaN
        float tsg = fexp2(-sc);
        float rr  = __fdividef(1.f, 1.f + tsg);
        long ob = ((long)(n * S + u) * S + a) * 2;
        *(float2*)(outp + ob) = make_float2(tsg * rr, rr);
    }
}

extern "C" void kernel_launch(void* const* d_in, const int* in_sizes, int n_in,
                              void* d_out, int out_size, void* d_ws, size_t ws_size,
                              hipStream_t stream) {
    const float* s_edge = (const float*)d_in[0];
    const float* s_sib  = (const float*)d_in[1];
    const float* s_cop  = (const float*)d_in[2];
    const float* s_grd  = (const float*)d_in[3];
    float* outp = (float*)d_out;
    (void)d_ws; (void)ws_size;          // workspace unused (no poison fills)

    k_fused<<<320, 960, 0, stream>>>(s_sib, s_cop, s_grd, s_edge, outp);
}

// Round 9
// 155.481 us; speedup vs baseline: 1.2504x; 1.0570x over previous
//
#include <hip/hip_runtime.h>
#include <hip/hip_fp16.h>

// LBP semantic dependency, channel-difference form, base-2 domain.
//   d'(x,p) = sp(x+p) - sp(x);  db[a,u] = edge + sum_{v!=a,u} sum_t d'-terms
// All db quantities in units of ln2. tp = e^p quantized fp16.
// R17 = R16 skeleton + ALGEBRAIC INSTRUCTION DIET:
//   R14==R16 (batching null, VALUBusy pinned 33%) => block is issue-bound on
//   the transcendental stream (~720 trans/thread x 4-8cy + 2200 VALU ~= the
//   measured 12us issue per SIMD; waves can't increase: 155KB slab set =>
//   1 block/CU, LDS-capacity-bound). Cut instructions, not latency:
//   (1) d2 term folded: log2(fma(E1,tA,1+tB)) - log2(1+tB+E1)   [3t+7v -> 2t+5v]
//   (2) d3 term folded: q=1+tA+E1u; r=fma(E1u,tB,1+tA); p=E2*q;
//       term = log2(fma(p,tA,r)) - log2(r+p)                    [4t+10v -> 2t+7v]
//   (3) ph1: sum log2(1+tp) -> log2(prod(1+tp)) per tensor (<=7 factors
//       <= 2^112, fp32-safe)                                    [80 log2 -> 12]
//   (4) cdb clamp +-100 -> +-45: folded intermediates <= ~2^110 (no inf);
//       saturation behavior identical over the fp16 tp range [2^-24, 2^17].
//   Trans/thread 720 -> ~410.

#define S    160
#define S2   25600            // 160*160
#define S3   4096000          // 160^3 (per-n slab, elements)
#define STR  162              // LDS slab row stride in halves (bank-spread pad)
#define C2E  1.4426950408889634f

__device__ __forceinline__ float fexp2(float x) { return __builtin_amdgcn_exp2f(x); }
__device__ __forceinline__ float flog2(float x) { return __builtin_amdgcn_logf(x); }
__device__ __forceinline__ float frcp(float x)  { return __builtin_amdgcn_rcpf(x); }
__device__ __forceinline__ float cdb(float x) {
    // +-45 (was +-100): terms are saturated beyond ~30 either way; 45 keeps
    // folded d2/d3 intermediates (<= E2*q*tA ~ 2^45+46+17) inside fp32.
    return fminf(fmaxf(x, -45.f), 45.f);
}
__device__ __forceinline__ float sp2t(float tp) { return flog2(1.f + tp); }
__device__ __forceinline__ float Ff(float x, float tp) {
    float tx = fexp2(x);
    return flog2(1.f + tx * tp) - flog2(1.f + tx);
}
__device__ __forceinline__ const float* selT(int t, const float* a,
                                             const float* b, const float* c) {
    return (t == 0) ? a : (t == 1) ? b : c;
}

// One block per slice (n,a). 960 threads (15 waves), 163,200B LDS -> 1 blk/CU.
__global__ __launch_bounds__(960)
void k_fused(const float* __restrict__ s_sib, const float* __restrict__ s_cop,
             const float* __restrict__ s_grd, const float* __restrict__ s_edge,
             float* __restrict__ outp)
{
    int slice = blockIdx.x;           // 0..319
    int a = slice % S, n = slice / S;
    int tid = threadIdx.x;
    int u4 = tid % 40, r = tid / 40;      // staging map (r 0..23, v = r+24i)
    int us = tid % S,  vs = tid / S;      // sweep map   (vs 0..5, v = 6k+vs)

    __shared__ __half tp3[3 * S * STR];   // tp3[t][v][u]           (155,520 B)
    __shared__ float  scr[1280];          // ph1 float4 partials / sweep partials (5,120 B)
    __shared__ float  db1s[S], db2s[S], E1[S], E2[S];               // (2,560 B)

    // ---- staging: all 960 threads; per tensor, thread loads v = r+24i
    // (i<6 all, i=6 only r<16), all misses in flight, converts, writes slab.
    // ph1 partial kept as per-tensor PRODUCT prod(1+tp) per u-column (<=7
    // factors of <2^16.001 -> <2^112, fp32-safe), one log2 per tensor.
    float4 acc = make_float4(0.f, 0.f, 0.f, 0.f);
    float edg = 0.f;
    if (tid < S) edg = s_edge[n * S2 + tid * S + a] * C2E;
    #pragma unroll
    for (int t = 0; t < 3; ++t) {
        const float* g = selT(t, s_sib, s_cop, s_grd)
                       + (long)n * S3 + (long)a * S + u4 * 4;
        float4 pv[7];
        #pragma unroll
        for (int i = 0; i < 6; ++i)
            pv[i] = *(const float4*)(g + (long)(r + 24 * i) * S2);
        if (r < 16) pv[6] = *(const float4*)(g + (long)(r + 144) * S2);
        float4 P = make_float4(1.f, 1.f, 1.f, 1.f);
        #pragma unroll
        for (int i = 0; i < 7; ++i) {
            if (i == 6 && r >= 16) break;
            int v = r + 24 * i;
            float t0 = fexp2(pv[i].x * C2E), t1 = fexp2(pv[i].y * C2E);
            float t2 = fexp2(pv[i].z * C2E), t3 = fexp2(pv[i].w * C2E);
            P.x = __builtin_fmaf(P.x, t0, P.x);   // P *= (1+t0)
            P.y = __builtin_fmaf(P.y, t1, P.y);
            P.z = __builtin_fmaf(P.z, t2, P.z);
            P.w = __builtin_fmaf(P.w, t3, P.w);
            __half* b = &tp3[t * (S * STR) + v * STR + u4 * 4];
            *(__half2*)(b)     = __floats2half2_rn(t0, t1);
            *(__half2*)(b + 2) = __floats2half2_rn(t2, t3);
        }
        acc.x += flog2(P.x); acc.y += flog2(P.y);
        acc.z += flog2(P.z); acc.w += flog2(P.w);
    }
    // ---- ph1 reduce: 24 r-groups -> 8 (3-stage RMW) -> db1
    float4* scr4 = (float4*)scr;
    if (r < 8) scr4[r * 40 + u4] = acc;
    __syncthreads();
    if (r >= 8 && r < 16) {
        float4 o = scr4[(r - 8) * 40 + u4];
        o.x += acc.x; o.y += acc.y; o.z += acc.z; o.w += acc.w;
        scr4[(r - 8) * 40 + u4] = o;
    }
    __syncthreads();
    if (r >= 16) {
        float4 o = scr4[(r - 16) * 40 + u4];
        o.x += acc.x; o.y += acc.y; o.z += acc.z; o.w += acc.w;
        scr4[(r - 16) * 40 + u4] = o;
    }
    __syncthreads();
    // ---- db1 + E1 (exclusion terms read from quantized slabs)
    if (tid < S) {
        int u = tid, cu4 = u >> 2, cc = u & 3;
        float s = 0.f;
        #pragma unroll
        for (int g2 = 0; g2 < 8; ++g2) s += scr[(g2 * 40 + cu4) * 4 + cc];
        float rr = edg + s - 480.f;
        #pragma unroll
        for (int t = 0; t < 3; ++t) {
            const __half* sl = &tp3[t * (S * STR)];
            float tpa = __half2float(sl[a * STR + u]);    // tp(v=a, u)
            rr -= (sp2t(tpa) - 1.f);
            if (u != a) {
                float tpu = __half2float(sl[u * STR + u]);
                rr -= (sp2t(tpu) - 1.f);
            }
        }
        db1s[u] = rr;
        E1[u] = fexp2(cdb(rr) + 1.f);
    }
    __syncthreads();

    // ---- d2 sweep, folded: term = log2(fma(E1,tA,1+tB)) - log2(1+tB+E1)
    float d2acc = 0.f;
    #pragma unroll
    for (int t = 0; t < 3; ++t) {
        const __half* sl = &tp3[t * (S * STR)];
        for (int kb = 0; kb < 6; ++kb) {
            float tA[4], tB[4], Ev[4];
            #pragma unroll
            for (int j = 0; j < 4; ++j) {
                int v = (kb * 4 + j) * 6 + vs;
                tA[j] = __half2float(sl[v * STR + us]);
                tB[j] = __half2float(sl[us * STR + v]);
                Ev[j] = E1[v];
            }
            #pragma unroll
            for (int j = 0; j < 4; ++j) {
                float B1 = 1.f + tB[j];
                float nm = __builtin_fmaf(Ev[j], tA[j], B1);
                float dn = B1 + Ev[j];
                d2acc += flog2(nm) - flog2(dn);
            }
        }
        #pragma unroll
        for (int k = 24; k < 27; ++k) {
            int v = k * 6 + vs;
            if (v < S) {
                float tA = __half2float(sl[v * STR + us]);
                float tB = __half2float(sl[us * STR + v]);
                float B1 = 1.f + tB;
                float nm = __builtin_fmaf(E1[v], tA, B1);
                float dn = B1 + E1[v];
                d2acc += flog2(nm) - flog2(dn);
            }
        }
    }
    scr[vs * S + us] = d2acc;
    __syncthreads();
    // ---- db2 (inline di2) + E2
    if (tid < S) {
        int u = tid;
        float sw = scr[u] + scr[S + u] + scr[2 * S + u] + scr[3 * S + u]
                 + scr[4 * S + u] + scr[5 * S + u];
        float db1a1 = cdb(db1s[a]) + 1.f;
        float db1u1 = cdb(db1s[u]) + 1.f;
        float sum = 0.f;
        #pragma unroll
        for (int t = 0; t < 3; ++t) {
            const __half* sl = &tp3[t * (S * STR)];
            float tpa  = __half2float(sl[a * STR + u]);   // tp(v=a, u)
            float tpba = __half2float(sl[u * STR + a]);   // tp(u, v=a)
            sum += Ff(db1a1 - sp2t(tpba), tpa);           // C2(v=a)
            if (u != a) {
                float tpu = __half2float(sl[u * STR + u]);
                sum += Ff(db1u1 - sp2t(tpu), tpu);        // C2(v=u)
            }
        }
        float d2v = edg - sum + sw;
        db2s[u] = d2v;
        E2[u] = fexp2(cdb(d2v));
    }
    __syncthreads();

    // ---- d3 sweep, folded: q=1+tA+E1u; r=fma(E1u,tB,1+tA); p=E2*q;
    //      term = log2(fma(p,tA,r)) - log2(r+p)
    float d3acc = 0.f;
    float E1u = E1[us];                  // 2^(db1[u]+1)
    #pragma unroll
    for (int t = 0; t < 3; ++t) {
        const __half* sl = &tp3[t * (S * STR)];
        for (int kb = 0; kb < 6; ++kb) {
            float tA[4], tB[4], Ev[4];
            #pragma unroll
            for (int j = 0; j < 4; ++j) {
                int v = (kb * 4 + j) * 6 + vs;
                tA[j] = __half2float(sl[v * STR + us]);
                tB[j] = __half2float(sl[us * STR + v]);
                Ev[j] = E2[v];
            }
            #pragma unroll
            for (int j = 0; j < 4; ++j) {
                float A1 = 1.f + tA[j];
                float q  = A1 + E1u;
                float rr = __builtin_fmaf(E1u, tB[j], A1);
                float p  = Ev[j] * q;
                float nm = __builtin_fmaf(p, tA[j], rr);
                float dn = rr + p;
                d3acc += flog2(nm) - flog2(dn);
            }
        }
        #pragma unroll
        for (int k = 24; k < 27; ++k) {
            int v = k * 6 + vs;
            if (v < S) {
                float tA = __half2float(sl[v * STR + us]);
                float tB = __half2float(sl[us * STR + v]);
                float A1 = 1.f + tA;
                float q  = A1 + E1u;
                float rr = __builtin_fmaf(E1u, tB, A1);
                float p  = E2[v] * q;
                float nm = __builtin_fmaf(p, tA, rr);
                float dn = rr + p;
                d3acc += flog2(nm) - flog2(dn);
            }
        }
    }
    scr[vs * S + us] = d3acc;
    __syncthreads();
    // ---- di3 + output
    if (tid < S) {
        int u = tid;
        float sw = scr[u] + scr[S + u] + scr[2 * S + u] + scr[3 * S + u]
                 + scr[4 * S + u] + scr[5 * S + u];
        float db1u1 = cdb(db1s[u]) + 1.f;
        float db2a = cdb(db2s[a]);
        float db2u = cdb(db2s[u]);
        float sum = 0.f;
        #pragma unroll
        for (int t = 0; t < 3; ++t) {
            const __half* sl = &tp3[t * (S * STR)];
            float tpa  = __half2float(sl[a * STR + u]);   // tp(v=a, u)
            float tpba = __half2float(sl[u * STR + a]);   // tp(u, v=a)
            float d2vu = Ff(db1u1 - sp2t(tpa), tpba);
            sum += Ff(db2a - d2vu, tpa);                  // C3(v=a)
            if (u != a) {
                float tpu = __half2float(sl[u * STR + u]);
                float d2  = Ff(db1u1 - sp2t(tpu), tpu);
                sum += Ff(db2u - d2, tpu);                // C3(v=u)
            }
        }
        float s = edg - sum + sw;
        float sc  = fminf(fmaxf(s, -60.f), 60.f);  // avoid exp2 overflow -> inf*0=NaN
        float tsg = fexp2(-sc);
        float rr  = __fdividef(1.f, 1.f + tsg);
        long ob = ((long)(n * S + u) * S + a) * 2;
        *(float2*)(outp + ob) = make_float2(tsg * rr, rr);
    }
}

extern "C" void kernel_launch(void* const* d_in, const int* in_sizes, int n_in,
                              void* d_out, int out_size, void* d_ws, size_t ws_size,
                              hipStream_t stream) {
    const float* s_edge = (const float*)d_in[0];
    const float* s_sib  = (const float*)d_in[1];
    const float* s_cop  = (const float*)d_in[2];
    const float* s_grd  = (const float*)d_in[3];
    float* outp = (float*)d_out;
    (void)d_ws; (void)ws_size;          // workspace unused (no poison fills)

    k_fused<<<320, 960, 0, stream>>>(s_sib, s_cop, s_grd, s_edge, outp);
}